// Round 8
// baseline (279.636 us; speedup 1.0000x reference)
//
#include <hip/hip_runtime.h>
#include <hip/hip_bf16.h>

// ---------------------------------------------------------------------------
// Tree-MLP, round 8: persistent blocks (512 blocks x 5 trees) with
// cross-tree pipelined x0 staging. Tree t+1's global loads are issued
// mid-way through tree t's phases and stay in flight across the
// lgkm-only barriers; compute structure identical to validated R7.
// ---------------------------------------------------------------------------

typedef __attribute__((ext_vector_type(8))) short s8v;   // 8 bf16
typedef __attribute__((ext_vector_type(4))) float f4v;   // MFMA C/D
typedef unsigned short u16;

__device__ __forceinline__ u16 f2bf(float f) {
    return __builtin_bit_cast(u16, __float2bfloat16(f));
}
__device__ __forceinline__ f4v mfma16(s8v a, s8v b, f4v c) {
    return __builtin_amdgcn_mfma_f32_16x16x32_bf16(a, b, c, 0, 0, 0);
}
// LDS swizzle for h-buffers: 8-granular XOR of h-index with row bits {0,2,3}
#define SWZ(r) ((((r) & 1) | (((r) >> 1) & 6)) << 3)

// tail A-frag from padded LDS row (cols 32..39, 35..39 zero); lq!=0 lanes zero
__device__ __forceinline__ s8v xtail_lds(const u16* xr, int lq) {
    s8v v = *(const s8v*)(xr + 32);
    if (lq != 0) v = (s8v){0,0,0,0,0,0,0,0};
    return v;
}

// ---------------------------------------------------------------------------
__global__ void prep_kernel(const float* __restrict__ W_emb, const float* __restrict__ b_emb,
                            const float* __restrict__ W0, const float* __restrict__ b0,
                            const float* __restrict__ W1, const float* __restrict__ b1,
                            u16* __restrict__ wt1, u16* __restrict__ wt0,
                            float* __restrict__ b1p, float* __restrict__ b0p)
{
    int idx = blockIdx.x * 256 + threadIdx.x;
    if (idx < 64 * 192) {
        int h = idx / 192, k = idx % 192;
        float v;
        if (k < 32) { v = 0.f; for (int e = 0; e < 64; e++) v = fmaf(W1[h*195+e], W_emb[e*32+k], v); }
        else if (k < 35)  v = W1[h*195 + 64 + (k - 32)];
        else if (k < 64)  v = 0.f;
        else              v = W1[h*195 + 67 + (k - 64)];   // hL(64) then hR(64)
        wt1[h*192 + k] = f2bf(v);
    } else if (idx < 64*192 + 64*64) {
        int j = idx - 64*192; int h = j >> 6, k = j & 63;
        float v;
        if (k < 32)      { v = 0.f; for (int e = 0; e < 64; e++) v = fmaf(W0[h*67+e], W_emb[e*32+k], v); }
        else if (k < 35)   v = W0[h*67 + 64 + (k - 32)];
        else               v = 0.f;
        wt0[h*64 + k] = f2bf(v);
    } else if (idx < 64*192 + 64*64 + 64) {
        int h = idx - (64*192 + 64*64);
        float v = b1[h];
        for (int e = 0; e < 64; e++) v = fmaf(W1[h*195+e], b_emb[e], v);
        b1p[h] = v;
    } else if (idx < 64*192 + 64*64 + 128) {
        int h = idx - (64*192 + 64*64 + 64);
        float v = b0[h];
        for (int e = 0; e < 64; e++) v = fmaf(W0[h*67+e], b_emb[e], v);
        b0p[h] = v;
    }
}

// ---------------------------------------------------------------------------
__global__ __launch_bounds__(512, 4) void tree_front(
    const float* __restrict__ x0,
    const u16* __restrict__ wt1, const u16* __restrict__ wt0,
    const float* __restrict__ b1p, const float* __restrict__ b0p,
    u16* __restrict__ h4)
{
    __shared__ __align__(16) u16 xleaf[257 * 40];  // leaf rows; later rows 0..126
    __shared__ __align__(16) u16 xmid [129 * 40];  // l7 rows 127..254
    __shared__ __align__(16) u16 buf0[256 * 64];   // 32 KB
    __shared__ __align__(16) u16 buf1[128 * 64];   // 16 KB

    const int tid = threadIdx.x;
    const int l  = tid & 63;
    const int w  = tid >> 6;   // 0..7
    const int c2 = w & 1;      // col half (32 cols)
    const int wr = w >> 1;     // row split 0..3
    const int lq = l >> 4;
    const int lm = l & 15;

    auto BAR = []() {
        asm volatile("s_waitcnt lgkmcnt(0)" ::: "memory");
        __builtin_amdgcn_s_barrier();
        asm volatile("" ::: "memory");
    };

    // zero pad columns 35..39 + guard rows (stay zero across all trees)
    if (tid < 256) {
        int b = tid * 40;
        for (int c = 35; c < 40; c++) xleaf[b + c] = 0;
        if (tid == 255) { for (int c = 0; c < 40; c++) xleaf[256 * 40 + c] = 0; }
    } else if (tid < 384) {
        int b = (tid - 256) * 40;
        for (int c = 35; c < 40; c++) xmid[b + c] = 0;
        if (tid == 383) { for (int c = 0; c < 40; c++) xmid[128 * 40 + c] = 0; }
    }

    // internal weights: resident for all 5 trees
    s8v wX[2][2], wH[2][4]; f4v bi1[2];
    #pragma unroll
    for (int cc = 0; cc < 2; cc++) {
        int col = c2*32 + cc*16 + lm;
        #pragma unroll
        for (int ks = 0; ks < 2; ks++) wX[cc][ks] = *(const s8v*)(wt1 + col*192 + ks*32 + lq*8);
        #pragma unroll
        for (int ks = 0; ks < 4; ks++) wH[cc][ks] = *(const s8v*)(wt1 + col*192 + 64 + ks*32 + lq*8);
        float bv = b1p[col];
        bi1[cc] = (f4v){bv, bv, bv, bv};
    }

    float sA[18], sB[9], sC[9];
    const float* xg = x0 + (size_t)(blockIdx.x * 5) * 511 * 35;

    auto issueA = [&](const float* g) {
        const float* gA = g + 255 * 35;    // leaf: 8960 dwords
        #pragma unroll
        for (int t = 0; t < 18; t++) { int i = t*512 + tid; sA[t] = (i < 8960) ? gA[i] : 0.f; }
    };
    auto issueB = [&](const float* g) {
        const float* gB = g + 127 * 35;    // l7: 4480 dwords
        #pragma unroll
        for (int t = 0; t < 9; t++)  { int i = t*512 + tid; sB[t] = (i < 4480) ? gB[i] : 0.f; }
    };
    auto issueC = [&](const float* g) {    // nodes 0..126: 4445 dwords
        #pragma unroll
        for (int t = 0; t < 9; t++)  { int i = t*512 + tid; sC[t] = (i < 4445) ? g[i] : 0.f; }
    };
    auto writeA = [&]() {
        #pragma unroll
        for (int t = 0; t < 18; t++) {
            int i = t*512 + tid;
            if (i < 8960) { int row = i / 35, col = i - row*35; xleaf[row*40 + col] = f2bf(sA[t]); }
        }
    };
    auto writeB = [&]() {
        #pragma unroll
        for (int t = 0; t < 9; t++) {
            int i = t*512 + tid;
            if (i < 4480) { int row = i / 35, col = i - row*35; xmid[row*40 + col] = f2bf(sB[t]); }
        }
    };
    auto writeC = [&]() {
        #pragma unroll
        for (int t = 0; t < 9; t++) {
            int i = t*512 + tid;
            if (i < 4445) { int row = i / 35, col = i - row*35; xleaf[row*40 + col] = f2bf(sC[t]); }
        }
    };

    auto store16 = [&](u16* bufW, int R0, const f4v& acc0, const f4v& acc1) {
        #pragma unroll
        for (int r = 0; r < 4; r++) {
            int ro = R0 + lq * 4 + r;
            int sw = SWZ(ro);
            bufW[ro*64 + ((c2*32      + lm) ^ sw)] = f2bf(fmaxf(acc0[r], 0.f));
            bufW[ro*64 + ((c2*32 + 16 + lm) ^ sw)] = f2bf(fmaxf(acc1[r], 0.f));
        }
    };
    auto ctile = [&](const u16* bufR, u16* bufW, const u16* xb, int xr0, int R0) {
        const u16* xr = xb + (xr0 + lm) * 40;
        s8v a0 = *(const s8v*)(xr + lq*8);
        s8v a1 = xtail_lds(xr, lq);
        f4v acc0 = bi1[0], acc1 = bi1[1];
        acc0 = mfma16(a0, wX[0][0], acc0);
        acc1 = mfma16(a0, wX[1][0], acc1);
        acc0 = mfma16(a1, wX[0][1], acc0);
        acc1 = mfma16(a1, wX[1][1], acc1);
        int g = R0 + lm;
        #pragma unroll
        for (int ks = 0; ks < 4; ks++) {
            int k0 = ks*32 + lq*8;
            int rr = 2*g + (k0 >> 6);
            s8v a = *(const s8v*)(bufR + rr*64 + ((k0 & 63) ^ SWZ(rr)));
            acc0 = mfma16(a, wH[0][ks], acc0);
            acc1 = mfma16(a, wH[1][ks], acc1);
        }
        store16(bufW, R0, acc0, acc1);
    };

    // prologue: issue tree 0's staging loads (only cold exposure)
    issueA(xg); issueB(xg); issueC(xg);

    #pragma unroll 1
    for (int it = 0; it < 5; it++) {
        const int p = blockIdx.x * 5 + it;
        const float* xgn = xg + 511 * 35;

        // leaf weights (per tree, transient; L2-hot)
        s8v wL[2][2]; f4v bi0[2];
        #pragma unroll
        for (int cc = 0; cc < 2; cc++) {
            int col = c2*32 + cc*16 + lm;
            wL[cc][0] = *(const s8v*)(wt0 + col*64 +      lq*8);
            wL[cc][1] = *(const s8v*)(wt0 + col*64 + 32 + lq*8);
            float bv = b0p[col];
            bi0[cc] = (f4v){bv, bv, bv, bv};
        }

        writeA();          // xleaf <- sA (vmcnt auto-waits on sA only)
        BAR();             // (1) xleaf ready

        // ---- leaf: 4 tiles/wave ----
        #pragma unroll
        for (int t = 0; t < 4; t++) {
            int R0 = (wr + 4*t) * 16;
            const u16* xr = xleaf + (R0 + lm) * 40;
            s8v a0 = *(const s8v*)(xr + lq*8);
            s8v a1 = xtail_lds(xr, lq);
            f4v acc0 = bi0[0], acc1 = bi0[1];
            acc0 = mfma16(a0, wL[0][0], acc0);
            acc1 = mfma16(a0, wL[1][0], acc1);
            acc0 = mfma16(a1, wL[0][1], acc0);
            acc1 = mfma16(a1, wL[1][1], acc1);
            store16(buf0, R0, acc0, acc1);
        }

        if (it < 4) issueA(xgn);   // next-tree leaf loads: in flight across BAR2..BAR6

        writeB();          // xmid <- sB
        BAR();             // (2) buf0 + xmid ready

        // ---- l7 (128 rows): buf0 -> buf1 ----
        ctile(buf0, buf1, xmid, wr * 16,       wr * 16);
        ctile(buf0, buf1, xmid, (wr + 4) * 16, (wr + 4) * 16);

        writeC();          // xleaf rows 0..126 <- sC
        BAR();             // (3) buf1 + xlow ready

        // ---- l6 (64 rows): buf1 -> buf0, x rows 63..126 ----
        ctile(buf1, buf0, xleaf, 63 + wr * 16, wr * 16);

        if (it < 4) { issueB(xgn); issueC(xgn); }   // in flight across BAR4..BAR6+(1)

        BAR();             // (4)
        // ---- l5 (32 rows): buf0 -> buf1, waves wr<2, x rows 31..62 ----
        if (wr < 2) ctile(buf0, buf1, xleaf, 31 + wr * 16, wr * 16);
        BAR();             // (5)
        // ---- l4 (16 rows): buf1 -> global h4, waves wr==0, x rows 15..30 ----
        if (wr == 0) {
            const u16* xr = xleaf + (15 + lm) * 40;
            s8v a0 = *(const s8v*)(xr + lq*8);
            s8v a1 = xtail_lds(xr, lq);
            f4v acc0 = bi1[0], acc1 = bi1[1];
            acc0 = mfma16(a0, wX[0][0], acc0);
            acc1 = mfma16(a0, wX[1][0], acc1);
            acc0 = mfma16(a1, wX[0][1], acc0);
            acc1 = mfma16(a1, wX[1][1], acc1);
            #pragma unroll
            for (int ks = 0; ks < 4; ks++) {
                int k0 = ks*32 + lq*8;
                int rr = 2*lm + (k0 >> 6);
                s8v a = *(const s8v*)(buf1 + rr*64 + ((k0 & 63) ^ SWZ(rr)));
                acc0 = mfma16(a, wH[0][ks], acc0);
                acc1 = mfma16(a, wH[1][ks], acc1);
            }
            #pragma unroll
            for (int r = 0; r < 4; r++) {
                h4[((size_t)p*16 + lq*4 + r) * 64 + c2*32      + lm] = f2bf(fmaxf(acc0[r], 0.f));
                h4[((size_t)p*16 + lq*4 + r) * 64 + c2*32 + 16 + lm] = f2bf(fmaxf(acc1[r], 0.f));
            }
        }
        BAR();             // (6) protect xleaf/buf reads before next tree's writes
        xg = xgn;
    }
}

// ---------------------------------------------------------------------------
// k3: block = tree p, ONE wave. l3..l0, children via LDS ping-pong, no
// barriers (intra-wave lgkmcnt ordering). All global loads hoisted to entry.
struct XL { float4 A, B, T; };
__device__ __forceinline__ s8v mk0(const XL& v) {
    s8v r;
    r[0]=(short)f2bf(v.A.x); r[1]=(short)f2bf(v.A.y); r[2]=(short)f2bf(v.A.z); r[3]=(short)f2bf(v.A.w);
    r[4]=(short)f2bf(v.B.x); r[5]=(short)f2bf(v.B.y); r[6]=(short)f2bf(v.B.z); r[7]=(short)f2bf(v.B.w);
    return r;
}
__device__ __forceinline__ s8v mk1(const XL& v) {
    s8v r = {0,0,0,0,0,0,0,0};
    r[0]=(short)f2bf(v.T.y); r[1]=(short)f2bf(v.T.z); r[2]=(short)f2bf(v.T.w);
    return r;
}

__global__ __launch_bounds__(64) void k3_tail(
    const float* __restrict__ x0,
    const u16* __restrict__ wt1, const float* __restrict__ b1p,
    const u16* __restrict__ h4, float* __restrict__ h0)
{
    __shared__ __align__(16) u16 tb0[32 * 64];
    __shared__ __align__(16) u16 tb1[32 * 64];
    const int l  = threadIdx.x;
    const int lq = l >> 4, lm = l & 15;
    const int p  = blockIdx.x;
    const float* xb = x0 + (size_t)p * 511 * 35;

    auto xload = [&](int lo) -> XL {
        const float* xr = xb + (size_t)(lo + lm) * 35;
        XL v;
        v.A = *(const float4*)(xr + lq * 8);
        v.B = *(const float4*)(xr + lq * 8 + 4);
        if (lq == 0) v.T = *(const float4*)(xr + 31);
        else         v.T = float4{0.f, 0.f, 0.f, 0.f};
        return v;
    };

    XL X3 = xload(7), X2 = xload(3), X1 = xload(1), X0v = xload(0);
    s8v ch[4];
    #pragma unroll
    for (int ks = 0; ks < 4; ks++) {
        int k0 = ks*32 + lq*8;
        int rr = 2*lm + (k0 >> 6);   // may overread into h0 region (allocated)
        ch[ks] = *(const s8v*)(h4 + ((size_t)p*16 + rr)*64 + (k0 & 63));
    }

    s8v wB[6][4]; f4v bi[4];
    #pragma unroll
    for (int ct = 0; ct < 4; ct++) {
        int col = ct*16 + lm;
        #pragma unroll
        for (int ks = 0; ks < 6; ks++) wB[ks][ct] = *(const s8v*)(wt1 + col*192 + ks*32 + lq*8);
        float bv = b1p[col];
        bi[ct] = (f4v){bv, bv, bv, bv};
    }

    f4v acc[4];
    auto store_lds = [&](u16* buf) {
        #pragma unroll
        for (int r = 0; r < 4; r++) {
            int ro = lq*4 + r; int sw = SWZ(ro);
            #pragma unroll
            for (int ct = 0; ct < 4; ct++)
                buf[ro*64 + ((ct*16 + lm) ^ sw)] = f2bf(fmaxf(acc[ct][r], 0.f));
        }
        asm volatile("s_waitcnt lgkmcnt(0)" ::: "memory");
    };

    {
        s8v a0 = mk0(X3), a1 = mk1(X3);
        #pragma unroll
        for (int ct = 0; ct < 4; ct++) {
            acc[ct] = bi[ct];
            acc[ct] = mfma16(a0, wB[0][ct], acc[ct]);
            acc[ct] = mfma16(a1, wB[1][ct], acc[ct]);
        }
        #pragma unroll
        for (int ks = 0; ks < 4; ks++)
            #pragma unroll
            for (int ct = 0; ct < 4; ct++) acc[ct] = mfma16(ch[ks], wB[2 + ks][ct], acc[ct]);
        store_lds(tb0);
    }

    auto level = [&](const XL& xv, const u16* bufR) {
        s8v a0 = mk0(xv), a1 = mk1(xv);
        #pragma unroll
        for (int ct = 0; ct < 4; ct++) {
            acc[ct] = bi[ct];
            acc[ct] = mfma16(a0, wB[0][ct], acc[ct]);
            acc[ct] = mfma16(a1, wB[1][ct], acc[ct]);
        }
        #pragma unroll
        for (int ks = 0; ks < 4; ks++) {
            int k0 = ks*32 + lq*8;
            int rr = 2*lm + (k0 >> 6);
            s8v a = *(const s8v*)(bufR + rr*64 + ((k0 & 63) ^ SWZ(rr)));
            #pragma unroll
            for (int ct = 0; ct < 4; ct++) acc[ct] = mfma16(a, wB[2 + ks][ct], acc[ct]);
        }
    };
    level(X2, tb0); store_lds(tb1);
    level(X1, tb1); store_lds(tb0);
    level(X0v, tb0);
    if (lq == 0) {
        #pragma unroll
        for (int ct = 0; ct < 4; ct++)
            h0[(size_t)p*64 + ct*16 + lm] = fmaxf(acc[ct][0], 0.f);
    }
}

// ---------------------------------------------------------------------------
__global__ void mean_kernel(const float* __restrict__ h0, float* __restrict__ mh)
{
    int idx = blockIdx.x * blockDim.x + threadIdx.x;   // 512*64
    if (idx < 512 * 64) {
        int g = idx >> 6, h = idx & 63;
        float s = 0.f;
        #pragma unroll
        for (int q = 0; q < 5; q++) s += h0[(size_t)(g * 5 + q) * 64 + h];
        mh[idx] = s * 0.2f;
    }
}

__global__ __launch_bounds__(64) void head_kernel(const float* __restrict__ x,
                                                  const float* __restrict__ mh,
                                                  const float* __restrict__ Wfc1,
                                                  const float* __restrict__ bfc1,
                                                  const float* __restrict__ Wfc2,
                                                  const float* __restrict__ bfc2,
                                                  float* __restrict__ out)
{
    __shared__ float sw[64];
    __shared__ float sh[64];
    int b = blockIdx.x, h = threadIdx.x;

    float a0 = 0.f, a1 = 0.f, a2 = 0.f, a3 = 0.f;
    const float* xr = x + (size_t)b * 512;
    for (int g = 0; g < 512; g += 4) {
        a0 = fmaf(xr[g + 0], mh[(g + 0) * 64 + h], a0);
        a1 = fmaf(xr[g + 1], mh[(g + 1) * 64 + h], a1);
        a2 = fmaf(xr[g + 2], mh[(g + 2) * 64 + h], a2);
        a3 = fmaf(xr[g + 3], mh[(g + 3) * 64 + h], a3);
    }
    sw[h] = (a0 + a1) + (a2 + a3);
    __syncthreads();

    float acc = bfc1[h];
    #pragma unroll 8
    for (int k = 0; k < 64; k++) acc = fmaf(Wfc1[h * 64 + k], sw[k], acc);
    sh[h] = fmaxf(acc, 0.f);
    __syncthreads();

    if (h < 8) {
        float o = bfc2[h];
        #pragma unroll 8
        for (int f = 0; f < 64; f++) o = fmaf(Wfc2[h * 64 + f], sh[f], o);
        out[(size_t)b * 8 + h] = o;
    }
}

// ---------------------------------------------------------------------------
extern "C" void kernel_launch(void* const* d_in, const int* in_sizes, int n_in,
                              void* d_out, int out_size, void* d_ws, size_t ws_size,
                              hipStream_t stream)
{
    (void)in_sizes; (void)n_in; (void)out_size; (void)ws_size;
    const float* x     = (const float*)d_in[0];
    const float* x0    = (const float*)d_in[1];
    const float* W_emb = (const float*)d_in[2];
    const float* b_emb = (const float*)d_in[3];
    const float* W0    = (const float*)d_in[4];
    const float* b0    = (const float*)d_in[5];
    const float* W1    = (const float*)d_in[6];
    const float* b1    = (const float*)d_in[7];
    const float* Wfc1  = (const float*)d_in[8];
    const float* bfc1  = (const float*)d_in[9];
    const float* Wfc2  = (const float*)d_in[10];
    const float* bfc2  = (const float*)d_in[11];
    float* out = (float*)d_out;

    u16* wt1   = (u16*)d_ws;                 // 64*192
    u16* wt0   = wt1 + 64 * 192;             // 64*64
    float* b1p = (float*)(wt0 + 64 * 64);
    float* b0p = b1p + 64;
    u16* h4    = (u16*)(b0p + 64);           // 2560*16*64 bf16
    float* h0  = (float*)(h4 + (size_t)2560 * 16 * 64);   // 2560*64 f32
    float* mh  = h0 + 2560 * 64;             // 512*64 f32

    prep_kernel<<<65, 256, 0, stream>>>(W_emb, b_emb, W0, b0, W1, b1, wt1, wt0, b1p, b0p);
    tree_front<<<512, 512, 0, stream>>>(x0, wt1, wt0, b1p, b0p, h4);
    k3_tail<<<2560, 64, 0, stream>>>(x0, wt1, b1p, h4, h0);
    mean_kernel<<<128, 256, 0, stream>>>(h0, mh);
    head_kernel<<<512, 64, 0, stream>>>(x, mh, Wfc1, bfc1, Wfc2, bfc2, out);
}

// Round 9
// 110.554 us; speedup vs baseline: 2.5294x; 2.5294x over previous
//
#include <hip/hip_runtime.h>
#include <hip/hip_bf16.h>

// ---------------------------------------------------------------------------
// Tree-MLP, round 9 = validated round-7 kernel with ONE change:
// __launch_bounds__(512, 2) on tree_front (was (512,4)).
// Theory: (512,4) capped the allocator at 64 VGPRs -> the 56-VGPR resident
// weight set was reloaded from L2 every phase (the ~6K cy/phase mystery).
// (512,2) permits up to 256 VGPRs; LDS (78.5KB) already limits occupancy to
// 2 blocks/CU, so the extra registers cost nothing.
// ---------------------------------------------------------------------------

typedef __attribute__((ext_vector_type(8))) short s8v;   // 8 bf16
typedef __attribute__((ext_vector_type(4))) float f4v;   // MFMA C/D
typedef unsigned short u16;

__device__ __forceinline__ u16 f2bf(float f) {
    return __builtin_bit_cast(u16, __float2bfloat16(f));
}
__device__ __forceinline__ f4v mfma16(s8v a, s8v b, f4v c) {
    return __builtin_amdgcn_mfma_f32_16x16x32_bf16(a, b, c, 0, 0, 0);
}
// LDS swizzle for h-buffers: 8-granular XOR of h-index with row bits {0,2,3}
#define SWZ(r) ((((r) & 1) | (((r) >> 1) & 6)) << 3)

// tail A-frag from padded LDS row (cols 32..39, 35..39 are zero); lanes with
// lq!=0 must supply zeros (their k >= 40 slots are padding of the K=64 step)
__device__ __forceinline__ s8v xtail_lds(const u16* xr, int lq) {
    s8v v = *(const s8v*)(xr + 32);
    if (lq != 0) v = (s8v){0,0,0,0,0,0,0,0};
    return v;
}

// ---------------------------------------------------------------------------
__global__ void prep_kernel(const float* __restrict__ W_emb, const float* __restrict__ b_emb,
                            const float* __restrict__ W0, const float* __restrict__ b0,
                            const float* __restrict__ W1, const float* __restrict__ b1,
                            u16* __restrict__ wt1, u16* __restrict__ wt0,
                            float* __restrict__ b1p, float* __restrict__ b0p)
{
    int idx = blockIdx.x * 256 + threadIdx.x;
    if (idx < 64 * 192) {
        int h = idx / 192, k = idx % 192;
        float v;
        if (k < 32) { v = 0.f; for (int e = 0; e < 64; e++) v = fmaf(W1[h*195+e], W_emb[e*32+k], v); }
        else if (k < 35)  v = W1[h*195 + 64 + (k - 32)];
        else if (k < 64)  v = 0.f;
        else              v = W1[h*195 + 67 + (k - 64)];   // hL(64) then hR(64)
        wt1[h*192 + k] = f2bf(v);
    } else if (idx < 64*192 + 64*64) {
        int j = idx - 64*192; int h = j >> 6, k = j & 63;
        float v;
        if (k < 32)      { v = 0.f; for (int e = 0; e < 64; e++) v = fmaf(W0[h*67+e], W_emb[e*32+k], v); }
        else if (k < 35)   v = W0[h*67 + 64 + (k - 32)];
        else               v = 0.f;
        wt0[h*64 + k] = f2bf(v);
    } else if (idx < 64*192 + 64*64 + 64) {
        int h = idx - (64*192 + 64*64);
        float v = b1[h];
        for (int e = 0; e < 64; e++) v = fmaf(W1[h*195+e], b_emb[e], v);
        b1p[h] = v;
    } else if (idx < 64*192 + 64*64 + 128) {
        int h = idx - (64*192 + 64*64 + 64);
        float v = b0[h];
        for (int e = 0; e < 64; e++) v = fmaf(W0[h*67+e], b_emb[e], v);
        b0p[h] = v;
    }
}

// ---------------------------------------------------------------------------
__global__ __launch_bounds__(512, 2) void tree_front(
    const float* __restrict__ x0,
    const u16* __restrict__ wt1, const u16* __restrict__ wt0,
    const float* __restrict__ b1p, const float* __restrict__ b0p,
    u16* __restrict__ h4)
{
    // padded x0 images: [row][40] bf16 (80B rows -> aligned b128 frags)
    __shared__ __align__(16) u16 xleaf[257 * 40];  // nodes 255..510; later reused for nodes 0..126
    __shared__ __align__(16) u16 xmid [129 * 40];  // nodes 127..254
    __shared__ __align__(16) u16 buf0[256 * 64];   // 32 KB
    __shared__ __align__(16) u16 buf1[128 * 64];   // 16 KB
    // total ~78.2 KB -> 2 blocks/CU (LDS-limited)

    const int tid = threadIdx.x;
    const int l  = tid & 63;
    const int w  = tid >> 6;   // 0..7
    const int c2 = w & 1;      // col half (32 cols)
    const int wr = w >> 1;     // row split 0..3
    const int lq = l >> 4;
    const int lm = l & 15;
    const int p  = blockIdx.x;
    const float* xg = x0 + (size_t)p * 511 * 35;

    auto BAR = []() {
        asm volatile("s_waitcnt lgkmcnt(0)" ::: "memory");
        __builtin_amdgcn_s_barrier();
        asm volatile("" ::: "memory");
    };

    // ---- S0: issue ALL x0 staging loads as coalesced dword streams ----
    float sA[18], sB[9], sC[9];
    const float* gA = xg + 255 * 35;   // leaf: 256 rows = 8960 dwords
    #pragma unroll
    for (int t = 0; t < 18; t++) { int i = t*512 + tid; sA[t] = (i < 8960) ? gA[i] : 0.f; }
    const float* gB = xg + 127 * 35;   // l7: 128 rows = 4480 dwords
    #pragma unroll
    for (int t = 0; t < 9; t++)  { int i = t*512 + tid; sB[t] = (i < 4480) ? gB[i] : 0.f; }
    const float* gC = xg;              // nodes 0..126: 4445 dwords
    #pragma unroll
    for (int t = 0; t < 9; t++)  { int i = t*512 + tid; sC[t] = (i < 4445) ? gC[i] : 0.f; }

    // zero pad columns 35..39 (tail-frag zeros; never overwritten afterwards)
    if (tid < 256) {
        int b = tid * 40;
        for (int c = 35; c < 40; c++) xleaf[b + c] = 0;
        if (tid == 255) {
            for (int c = 0; c < 40; c++) xleaf[256 * 40 + c] = 0;   // guard row
        }
    } else if (tid < 384) {
        int b = (tid - 256) * 40;
        for (int c = 35; c < 40; c++) xmid[b + c] = 0;
        if (tid == 383) {
            for (int c = 0; c < 40; c++) xmid[128 * 40 + c] = 0;    // guard row
        }
    }

    // leaf weights
    s8v wL[2][2]; f4v bi0[2];
    #pragma unroll
    for (int cc = 0; cc < 2; cc++) {
        int col = c2*32 + cc*16 + lm;
        wL[cc][0] = *(const s8v*)(wt0 + col*64 +      lq*8);
        wL[cc][1] = *(const s8v*)(wt0 + col*64 + 32 + lq*8);
        float bv = b0p[col];
        bi0[cc] = (f4v){bv, bv, bv, bv};
    }

    // write leaf region (waits only on sA loads)
    #pragma unroll
    for (int t = 0; t < 18; t++) {
        int i = t*512 + tid;
        if (i < 8960) { int row = i / 35, col = i - row*35; xleaf[row*40 + col] = f2bf(sA[t]); }
    }
    BAR();   // xleaf ready

    auto store16 = [&](u16* bufW, int R0, const f4v& acc0, const f4v& acc1) {
        #pragma unroll
        for (int r = 0; r < 4; r++) {
            int ro = R0 + lq * 4 + r;
            int sw = SWZ(ro);
            bufW[ro*64 + ((c2*32      + lm) ^ sw)] = f2bf(fmaxf(acc0[r], 0.f));
            bufW[ro*64 + ((c2*32 + 16 + lm) ^ sw)] = f2bf(fmaxf(acc1[r], 0.f));
        }
    };

    // ---- leaf: 4 tiles/wave from LDS frags ----
    #pragma unroll
    for (int t = 0; t < 4; t++) {
        int R0 = (wr + 4*t) * 16;
        const u16* xr = xleaf + (R0 + lm) * 40;
        s8v a0 = *(const s8v*)(xr + lq*8);
        s8v a1 = xtail_lds(xr, lq);
        f4v acc0 = bi0[0], acc1 = bi0[1];
        acc0 = mfma16(a0, wL[0][0], acc0);
        acc1 = mfma16(a0, wL[1][0], acc1);
        acc0 = mfma16(a1, wL[0][1], acc0);
        acc1 = mfma16(a1, wL[1][1], acc1);
        store16(buf0, R0, acc0, acc1);
    }

    // internal weights (resident for all internal levels)
    s8v wX[2][2], wH[2][4]; f4v bi1[2];
    #pragma unroll
    for (int cc = 0; cc < 2; cc++) {
        int col = c2*32 + cc*16 + lm;
        #pragma unroll
        for (int ks = 0; ks < 2; ks++) wX[cc][ks] = *(const s8v*)(wt1 + col*192 + ks*32 + lq*8);
        #pragma unroll
        for (int ks = 0; ks < 4; ks++) wH[cc][ks] = *(const s8v*)(wt1 + col*192 + 64 + ks*32 + lq*8);
        float bv = b1p[col];
        bi1[cc] = (f4v){bv, bv, bv, bv};
    }

    // write l7 x-region during leaf->l7 window
    #pragma unroll
    for (int t = 0; t < 9; t++) {
        int i = t*512 + tid;
        if (i < 4480) { int row = i / 35, col = i - row*35; xmid[row*40 + col] = f2bf(sB[t]); }
    }
    BAR();   // buf0 + xmid ready

    auto ctile = [&](const u16* bufR, u16* bufW, const u16* xb, int xr0, int R0) {
        const u16* xr = xb + (xr0 + lm) * 40;
        s8v a0 = *(const s8v*)(xr + lq*8);
        s8v a1 = xtail_lds(xr, lq);
        f4v acc0 = bi1[0], acc1 = bi1[1];
        acc0 = mfma16(a0, wX[0][0], acc0);
        acc1 = mfma16(a0, wX[1][0], acc1);
        acc0 = mfma16(a1, wX[0][1], acc0);
        acc1 = mfma16(a1, wX[1][1], acc1);
        int g = R0 + lm;
        #pragma unroll
        for (int ks = 0; ks < 4; ks++) {
            int k0 = ks*32 + lq*8;
            int rr = 2*g + (k0 >> 6);
            s8v a = *(const s8v*)(bufR + rr*64 + ((k0 & 63) ^ SWZ(rr)));
            acc0 = mfma16(a, wH[0][ks], acc0);
            acc1 = mfma16(a, wH[1][ks], acc1);
        }
        store16(bufW, R0, acc0, acc1);
    };

    // ---- l7 (128 rows): buf0 -> buf1, x from xmid ----
    ctile(buf0, buf1, xmid, wr * 16,        wr * 16);
    ctile(buf0, buf1, xmid, (wr + 4) * 16,  (wr + 4) * 16);

    // write remaining x-region (nodes 0..126) into xleaf (free after leaf)
    #pragma unroll
    for (int t = 0; t < 9; t++) {
        int i = t*512 + tid;
        if (i < 4445) { int row = i / 35, col = i - row*35; xleaf[row*40 + col] = f2bf(sC[t]); }
    }
    BAR();   // buf1 + xrest ready

    // ---- l6 (64 rows): buf1 -> buf0, x rows 63..126 ----
    ctile(buf1, buf0, xleaf, 63 + wr * 16, wr * 16);
    BAR();
    // ---- l5 (32 rows): buf0 -> buf1, waves wr<2, x rows 31..62 ----
    if (wr < 2) ctile(buf0, buf1, xleaf, 31 + wr * 16, wr * 16);
    BAR();
    // ---- l4 (16 rows): buf1 -> global h4, waves wr==0, x rows 15..30 ----
    if (wr == 0) {
        const u16* xr = xleaf + (15 + lm) * 40;
        s8v a0 = *(const s8v*)(xr + lq*8);
        s8v a1 = xtail_lds(xr, lq);
        f4v acc0 = bi1[0], acc1 = bi1[1];
        acc0 = mfma16(a0, wX[0][0], acc0);
        acc1 = mfma16(a0, wX[1][0], acc1);
        acc0 = mfma16(a1, wX[0][1], acc0);
        acc1 = mfma16(a1, wX[1][1], acc1);
        #pragma unroll
        for (int ks = 0; ks < 4; ks++) {
            int k0 = ks*32 + lq*8;
            int rr = 2*lm + (k0 >> 6);
            s8v a = *(const s8v*)(buf1 + rr*64 + ((k0 & 63) ^ SWZ(rr)));
            acc0 = mfma16(a, wH[0][ks], acc0);
            acc1 = mfma16(a, wH[1][ks], acc1);
        }
        #pragma unroll
        for (int r = 0; r < 4; r++) {
            h4[((size_t)p*16 + lq*4 + r) * 64 + c2*32      + lm] = f2bf(fmaxf(acc0[r], 0.f));
            h4[((size_t)p*16 + lq*4 + r) * 64 + c2*32 + 16 + lm] = f2bf(fmaxf(acc1[r], 0.f));
        }
    }
}

// ---------------------------------------------------------------------------
// k3: block = tree p, ONE wave. l3..l0, children via LDS ping-pong, no
// barriers (intra-wave lgkmcnt ordering). All global loads hoisted to entry.
struct XL { float4 A, B, T; };
__device__ __forceinline__ s8v mk0(const XL& v) {
    s8v r;
    r[0]=(short)f2bf(v.A.x); r[1]=(short)f2bf(v.A.y); r[2]=(short)f2bf(v.A.z); r[3]=(short)f2bf(v.A.w);
    r[4]=(short)f2bf(v.B.x); r[5]=(short)f2bf(v.B.y); r[6]=(short)f2bf(v.B.z); r[7]=(short)f2bf(v.B.w);
    return r;
}
__device__ __forceinline__ s8v mk1(const XL& v) {
    s8v r = {0,0,0,0,0,0,0,0};
    r[0]=(short)f2bf(v.T.y); r[1]=(short)f2bf(v.T.z); r[2]=(short)f2bf(v.T.w);
    return r;
}

__global__ __launch_bounds__(64) void k3_tail(
    const float* __restrict__ x0,
    const u16* __restrict__ wt1, const float* __restrict__ b1p,
    const u16* __restrict__ h4, float* __restrict__ h0)
{
    __shared__ __align__(16) u16 tb0[32 * 64];
    __shared__ __align__(16) u16 tb1[32 * 64];
    const int l  = threadIdx.x;
    const int lq = l >> 4, lm = l & 15;
    const int p  = blockIdx.x;
    const float* xb = x0 + (size_t)p * 511 * 35;

    auto xload = [&](int lo) -> XL {
        const float* xr = xb + (size_t)(lo + lm) * 35;
        XL v;
        v.A = *(const float4*)(xr + lq * 8);
        v.B = *(const float4*)(xr + lq * 8 + 4);
        if (lq == 0) v.T = *(const float4*)(xr + 31);
        else         v.T = float4{0.f, 0.f, 0.f, 0.f};
        return v;
    };

    XL X3 = xload(7), X2 = xload(3), X1 = xload(1), X0v = xload(0);
    s8v ch[4];
    #pragma unroll
    for (int ks = 0; ks < 4; ks++) {
        int k0 = ks*32 + lq*8;
        int rr = 2*lm + (k0 >> 6);   // may overread into h0 region (allocated)
        ch[ks] = *(const s8v*)(h4 + ((size_t)p*16 + rr)*64 + (k0 & 63));
    }

    s8v wB[6][4]; f4v bi[4];
    #pragma unroll
    for (int ct = 0; ct < 4; ct++) {
        int col = ct*16 + lm;
        #pragma unroll
        for (int ks = 0; ks < 6; ks++) wB[ks][ct] = *(const s8v*)(wt1 + col*192 + ks*32 + lq*8);
        float bv = b1p[col];
        bi[ct] = (f4v){bv, bv, bv, bv};
    }

    f4v acc[4];
    auto store_lds = [&](u16* buf) {
        #pragma unroll
        for (int r = 0; r < 4; r++) {
            int ro = lq*4 + r; int sw = SWZ(ro);
            #pragma unroll
            for (int ct = 0; ct < 4; ct++)
                buf[ro*64 + ((ct*16 + lm) ^ sw)] = f2bf(fmaxf(acc[ct][r], 0.f));
        }
        asm volatile("s_waitcnt lgkmcnt(0)" ::: "memory");
    };

    {
        s8v a0 = mk0(X3), a1 = mk1(X3);
        #pragma unroll
        for (int ct = 0; ct < 4; ct++) {
            acc[ct] = bi[ct];
            acc[ct] = mfma16(a0, wB[0][ct], acc[ct]);
            acc[ct] = mfma16(a1, wB[1][ct], acc[ct]);
        }
        #pragma unroll
        for (int ks = 0; ks < 4; ks++)
            #pragma unroll
            for (int ct = 0; ct < 4; ct++) acc[ct] = mfma16(ch[ks], wB[2 + ks][ct], acc[ct]);
        store_lds(tb0);
    }

    auto level = [&](const XL& xv, const u16* bufR) {
        s8v a0 = mk0(xv), a1 = mk1(xv);
        #pragma unroll
        for (int ct = 0; ct < 4; ct++) {
            acc[ct] = bi[ct];
            acc[ct] = mfma16(a0, wB[0][ct], acc[ct]);
            acc[ct] = mfma16(a1, wB[1][ct], acc[ct]);
        }
        #pragma unroll
        for (int ks = 0; ks < 4; ks++) {
            int k0 = ks*32 + lq*8;
            int rr = 2*lm + (k0 >> 6);
            s8v a = *(const s8v*)(bufR + rr*64 + ((k0 & 63) ^ SWZ(rr)));
            #pragma unroll
            for (int ct = 0; ct < 4; ct++) acc[ct] = mfma16(a, wB[2 + ks][ct], acc[ct]);
        }
    };
    level(X2, tb0); store_lds(tb1);
    level(X1, tb1); store_lds(tb0);
    level(X0v, tb0);
    if (lq == 0) {
        #pragma unroll
        for (int ct = 0; ct < 4; ct++)
            h0[(size_t)p*64 + ct*16 + lm] = fmaxf(acc[ct][0], 0.f);
    }
}

// ---------------------------------------------------------------------------
__global__ void mean_kernel(const float* __restrict__ h0, float* __restrict__ mh)
{
    int idx = blockIdx.x * blockDim.x + threadIdx.x;   // 512*64
    if (idx < 512 * 64) {
        int g = idx >> 6, h = idx & 63;
        float s = 0.f;
        #pragma unroll
        for (int q = 0; q < 5; q++) s += h0[(size_t)(g * 5 + q) * 64 + h];
        mh[idx] = s * 0.2f;
    }
}

__global__ __launch_bounds__(64) void head_kernel(const float* __restrict__ x,
                                                  const float* __restrict__ mh,
                                                  const float* __restrict__ Wfc1,
                                                  const float* __restrict__ bfc1,
                                                  const float* __restrict__ Wfc2,
                                                  const float* __restrict__ bfc2,
                                                  float* __restrict__ out)
{
    __shared__ float sw[64];
    __shared__ float sh[64];
    int b = blockIdx.x, h = threadIdx.x;

    float a0 = 0.f, a1 = 0.f, a2 = 0.f, a3 = 0.f;
    const float* xr = x + (size_t)b * 512;
    for (int g = 0; g < 512; g += 4) {
        a0 = fmaf(xr[g + 0], mh[(g + 0) * 64 + h], a0);
        a1 = fmaf(xr[g + 1], mh[(g + 1) * 64 + h], a1);
        a2 = fmaf(xr[g + 2], mh[(g + 2) * 64 + h], a2);
        a3 = fmaf(xr[g + 3], mh[(g + 3) * 64 + h], a3);
    }
    sw[h] = (a0 + a1) + (a2 + a3);
    __syncthreads();

    float acc = bfc1[h];
    #pragma unroll 8
    for (int k = 0; k < 64; k++) acc = fmaf(Wfc1[h * 64 + k], sw[k], acc);
    sh[h] = fmaxf(acc, 0.f);
    __syncthreads();

    if (h < 8) {
        float o = bfc2[h];
        #pragma unroll 8
        for (int f = 0; f < 64; f++) o = fmaf(Wfc2[h * 64 + f], sh[f], o);
        out[(size_t)b * 8 + h] = o;
    }
}

// ---------------------------------------------------------------------------
extern "C" void kernel_launch(void* const* d_in, const int* in_sizes, int n_in,
                              void* d_out, int out_size, void* d_ws, size_t ws_size,
                              hipStream_t stream)
{
    (void)in_sizes; (void)n_in; (void)out_size; (void)ws_size;
    const float* x     = (const float*)d_in[0];
    const float* x0    = (const float*)d_in[1];
    const float* W_emb = (const float*)d_in[2];
    const float* b_emb = (const float*)d_in[3];
    const float* W0    = (const float*)d_in[4];
    const float* b0    = (const float*)d_in[5];
    const float* W1    = (const float*)d_in[6];
    const float* b1    = (const float*)d_in[7];
    const float* Wfc1  = (const float*)d_in[8];
    const float* bfc1  = (const float*)d_in[9];
    const float* Wfc2  = (const float*)d_in[10];
    const float* bfc2  = (const float*)d_in[11];
    float* out = (float*)d_out;

    u16* wt1   = (u16*)d_ws;                 // 64*192
    u16* wt0   = wt1 + 64 * 192;             // 64*64
    float* b1p = (float*)(wt0 + 64 * 64);
    float* b0p = b1p + 64;
    u16* h4    = (u16*)(b0p + 64);           // 2560*16*64 bf16
    float* h0  = (float*)(h4 + (size_t)2560 * 16 * 64);   // 2560*64 f32
    float* mh  = h0 + 2560 * 64;             // 512*64 f32

    prep_kernel<<<65, 256, 0, stream>>>(W_emb, b_emb, W0, b0, W1, b1, wt1, wt0, b1p, b0p);
    tree_front<<<2560, 512, 0, stream>>>(x0, wt1, wt0, b1p, b0p, h4);
    k3_tail<<<2560, 64, 0, stream>>>(x0, wt1, b1p, h4, h0);
    mean_kernel<<<128, 256, 0, stream>>>(h0, mh);
    head_kernel<<<512, 64, 0, stream>>>(x, mh, Wfc1, bfc1, Wfc2, bfc2, out);
}

// Round 10
// 95.693 us; speedup vs baseline: 2.9222x; 1.1553x over previous
//
#include <hip/hip_runtime.h>
#include <hip/hip_bf16.h>

// ---------------------------------------------------------------------------
// Round 10: barrier-free per-wave subtree chains.
// Swapped MFMA (A=W, B=activations) with sigma-permuted W columns makes each
// level's output land lane-local in exactly the next level's B-frag layout:
// h passes leaf->l7->l6 entirely in registers (no LDS, no barriers, no
// cross-lane ops). Block = 2 trees x 4 chains = 8 free-running waves;
// only 2 barriers per block (weight staging, l6 buffer for l5).
// l5+l4 chained per tree-wave -> h4 -> validated k3_tail (l3..l0) unchanged.
// ---------------------------------------------------------------------------

typedef __attribute__((ext_vector_type(8))) short s8v;   // 8 bf16
typedef __attribute__((ext_vector_type(4))) float f4v;   // MFMA C/D
typedef unsigned short u16;
typedef unsigned int   u32;

__device__ __forceinline__ u16 f2bf(float f) {
    return __builtin_bit_cast(u16, __float2bfloat16(f));
}
__device__ __forceinline__ f4v mfma16(s8v a, s8v b, f4v c) {
    return __builtin_amdgcn_mfma_f32_16x16x32_bf16(a, b, c, 0, 0, 0);
}
#define SWZ(r) ((((r) & 1) | (((r) >> 1) & 6)) << 3)

// relu + pack 2 f32 -> dword of 2 bf16 (lo = first)
__device__ __forceinline__ u32 pk2(float a, float b) {
    return (u32)f2bf(fmaxf(a, 0.f)) | ((u32)f2bf(fmaxf(b, 0.f)) << 16);
}
// pack chunk pair (h=0, h=1) of one s-window into the consumer B-frag
__device__ __forceinline__ s8v pkfrag(f4v h0, f4v h1) {
    int4 d;
    d.x = (int)pk2(h0[0], h0[1]); d.y = (int)pk2(h0[2], h0[3]);
    d.z = (int)pk2(h1[0], h1[1]); d.w = (int)pk2(h1[2], h1[3]);
    return __builtin_bit_cast(s8v, d);
}
// x B-frags: lane rho = l&15 is the tile row; k = 8*lq + j
__device__ __forceinline__ s8v xB0(const float* __restrict__ xr, int lq) {
    float4 A = *(const float4*)(xr + lq * 8);
    float4 B = *(const float4*)(xr + lq * 8 + 4);
    s8v r;
    r[0]=(short)f2bf(A.x); r[1]=(short)f2bf(A.y); r[2]=(short)f2bf(A.z); r[3]=(short)f2bf(A.w);
    r[4]=(short)f2bf(B.x); r[5]=(short)f2bf(B.y); r[6]=(short)f2bf(B.z); r[7]=(short)f2bf(B.w);
    return r;
}
__device__ __forceinline__ s8v xB1(const float* __restrict__ xr, int lq) {
    s8v r = (s8v){0,0,0,0,0,0,0,0};
    if (lq == 0) {
        float4 T = *(const float4*)(xr + 31);   // k31..34
        r[0]=(short)f2bf(T.y); r[1]=(short)f2bf(T.z); r[2]=(short)f2bf(T.w);
    }
    return r;
}
__device__ __forceinline__ s8v wread(const u16* w, int stride, int row, int ks, int lq) {
    return *(const s8v*)(w + row * stride + ks * 32 + lq * 8);
}
__device__ __forceinline__ f4v bias4(const float* __restrict__ b) {
    float4 t = *(const float4*)b; return (f4v){t.x, t.y, t.z, t.w};
}
// sigma-permuted W row for consumed levels: col(rho) = 32s + 8*(rho>>2) + 4h + (rho&3)
__device__ __forceinline__ int sigp(int rho, int s, int h) {
    return 32*s + 4*h + ((rho & 12) << 1) + (rho & 3);
}

// ---------------------------------------------------------------------------
__global__ void prep_kernel(const float* __restrict__ W_emb, const float* __restrict__ b_emb,
                            const float* __restrict__ W0, const float* __restrict__ b0,
                            const float* __restrict__ W1, const float* __restrict__ b1,
                            u16* __restrict__ wt1, u16* __restrict__ wt0,
                            float* __restrict__ b1p, float* __restrict__ b0p)
{
    int idx = blockIdx.x * 256 + threadIdx.x;
    if (idx < 64 * 192) {
        int h = idx / 192, k = idx % 192;
        float v;
        if (k < 32) { v = 0.f; for (int e = 0; e < 64; e++) v = fmaf(W1[h*195+e], W_emb[e*32+k], v); }
        else if (k < 35)  v = W1[h*195 + 64 + (k - 32)];
        else if (k < 64)  v = 0.f;
        else              v = W1[h*195 + 67 + (k - 64)];   // hL(64) then hR(64)
        wt1[h*192 + k] = f2bf(v);
    } else if (idx < 64*192 + 64*64) {
        int j = idx - 64*192; int h = j >> 6, k = j & 63;
        float v;
        if (k < 32)      { v = 0.f; for (int e = 0; e < 64; e++) v = fmaf(W0[h*67+e], W_emb[e*32+k], v); }
        else if (k < 35)   v = W0[h*67 + 64 + (k - 32)];
        else               v = 0.f;
        wt0[h*64 + k] = f2bf(v);
    } else if (idx < 64*192 + 64*64 + 64) {
        int h = idx - (64*192 + 64*64);
        float v = b1[h];
        for (int e = 0; e < 64; e++) v = fmaf(W1[h*195+e], b_emb[e], v);
        b1p[h] = v;
    } else if (idx < 64*192 + 64*64 + 128) {
        int h = idx - (64*192 + 64*64 + 64);
        float v = b0[h];
        for (int e = 0; e < 64; e++) v = fmaf(W0[h*67+e], b_emb[e], v);
        b0p[h] = v;
    }
}

// ---------------------------------------------------------------------------
__global__ __launch_bounds__(512, 2) void tree_chain(
    const float* __restrict__ x0,
    const u16* __restrict__ wt1g, const u16* __restrict__ wt0g,
    const float* __restrict__ b1p, const float* __restrict__ b0p,
    u16* __restrict__ h4)
{
    __shared__ __align__(16) u16 wt1s[64 * 200];        // pad stride 200
    __shared__ __align__(16) u16 wt0s[64 * 40 + 64];    // pad stride 40 + guard
    __shared__ __align__(16) u16 buf6[2 * 64 * 64];     // l6 out, SWZ'd, 2 trees

    const int tid = threadIdx.x;
    const int l   = tid & 63;
    const int w   = tid >> 6;      // 0..7
    const int lq  = l >> 4;
    const int rho = l & 15;
    const int tsel = w >> 2;       // tree within block
    const int c    = w & 3;        // chain (16 l6 nodes)
    const int tree = blockIdx.x * 2 + tsel;
    const float* xb = x0 + (size_t)tree * 511 * 35;

    // ---- stage weights into padded LDS (coalesced dwords) ----
    {
        u32* d1 = (u32*)wt1s; const u32* s1 = (const u32*)wt1g;
        #pragma unroll
        for (int t = 0; t < 12; t++) {
            int i = t*512 + tid;                 // 6144 dwords exactly
            int row = i / 96, kk = i - row*96;
            d1[row*100 + kk] = s1[row*96 + kk];
        }
        u32* d0 = (u32*)wt0s; const u32* s0 = (const u32*)wt0g;
        #pragma unroll
        for (int t = 0; t < 3; t++) {
            int i = t*512 + tid;
            if (i < 1280) { int row = i / 20, kk = i - row*20; d0[row*20 + kk] = s0[row*32 + kk]; }
        }
        if (tid < 32) ((u32*)(wt0s + 64*40))[tid] = 0;   // guard (x-tail overread)
    }
    __syncthreads();

    // ================= chain: leaf -> l7 -> l6 (no barriers) =================
    // ---- leaf: 4 parity tiles TLq (rows = leaf node 64c + 4*rho + q) ----
    s8v TLf[4][2];
    {
        s8v WL[4][2]; f4v bL[4];
        #pragma unroll
        for (int i = 0; i < 4; i++) {
            int s = i >> 1, h = i & 1;
            int sg = sigp(rho, s, h);
            WL[i][0] = wread(wt0s, 40, sg, 0, lq);
            WL[i][1] = wread(wt0s, 40, sg, 1, lq);
            bL[i] = bias4(b0p + 32*s + 8*lq + 4*h);
        }
        #pragma unroll
        for (int q = 0; q < 4; q++) {
            const float* xr = xb + (size_t)(255 + 64*c + 4*rho + q) * 35;
            s8v xa = xB0(xr, lq), xt = xB1(xr, lq);
            f4v a0 = bL[0], a1 = bL[1], a2 = bL[2], a3 = bL[3];
            a0 = mfma16(WL[0][0], xa, a0); a0 = mfma16(WL[0][1], xt, a0);
            a1 = mfma16(WL[1][0], xa, a1); a1 = mfma16(WL[1][1], xt, a1);
            a2 = mfma16(WL[2][0], xa, a2); a2 = mfma16(WL[2][1], xt, a2);
            a3 = mfma16(WL[3][0], xa, a3); a3 = mfma16(WL[3][1], xt, a3);
            TLf[q][0] = pkfrag(a0, a1);
            TLf[q][1] = pkfrag(a2, a3);
        }
    }

    // ---- l7: parity tiles E (node 127+32c+2rho) / O (+1) ----
    s8v T7E0, T7E1, T7O0, T7O1;
    {
        f4v aE[4], aO[4];
        #pragma unroll
        for (int i = 0; i < 4; i++) {
            f4v b = bias4(b1p + 32*(i>>1) + 8*lq + 4*(i&1));
            aE[i] = b; aO[i] = b;
        }
        {
            const float* xrE = xb + (size_t)(127 + 32*c + 2*rho) * 35;
            const float* xrO = xrE + 35;
            s8v xE0 = xB0(xrE, lq), xE1 = xB1(xrE, lq);
            s8v xO0 = xB0(xrO, lq), xO1 = xB1(xrO, lq);
            #pragma unroll
            for (int i = 0; i < 4; i++) {
                int sg = sigp(rho, i>>1, i&1);
                s8v w0 = wread(wt1s, 200, sg, 0, lq);
                s8v w1 = wread(wt1s, 200, sg, 1, lq);
                aE[i] = mfma16(w0, xE0, aE[i]); aE[i] = mfma16(w1, xE1, aE[i]);
                aO[i] = mfma16(w0, xO0, aO[i]); aO[i] = mfma16(w1, xO1, aO[i]);
            }
        }
        #pragma unroll
        for (int i = 0; i < 4; i++) {
            int sg = sigp(rho, i>>1, i&1);
            s8v w2 = wread(wt1s, 200, sg, 2, lq);
            s8v w3 = wread(wt1s, 200, sg, 3, lq);
            s8v w4 = wread(wt1s, 200, sg, 4, lq);
            s8v w5 = wread(wt1s, 200, sg, 5, lq);
            aE[i] = mfma16(w2, TLf[0][0], aE[i]); aE[i] = mfma16(w3, TLf[0][1], aE[i]);
            aE[i] = mfma16(w4, TLf[1][0], aE[i]); aE[i] = mfma16(w5, TLf[1][1], aE[i]);
            aO[i] = mfma16(w2, TLf[2][0], aO[i]); aO[i] = mfma16(w3, TLf[2][1], aO[i]);
            aO[i] = mfma16(w4, TLf[3][0], aO[i]); aO[i] = mfma16(w5, TLf[3][1], aO[i]);
        }
        T7E0 = pkfrag(aE[0], aE[1]); T7E1 = pkfrag(aE[2], aE[3]);
        T7O0 = pkfrag(aO[0], aO[1]); T7O1 = pkfrag(aO[2], aO[3]);
    }

    // ---- l6: natural col order, store to buf6 (SWZ'd rows) ----
    {
        const float* xr6 = xb + (size_t)(63 + 16*c + rho) * 35;
        s8v x60 = xB0(xr6, lq), x61 = xB1(xr6, lq);
        u16* b6 = buf6 + tsel * 4096;
        int r6 = 16*c + rho;
        #pragma unroll
        for (int cc = 0; cc < 4; cc++) {
            f4v a = bias4(b1p + 16*cc + 4*lq);
            int sg = 16*cc + rho;
            s8v w0 = wread(wt1s, 200, sg, 0, lq);
            s8v w1 = wread(wt1s, 200, sg, 1, lq);
            s8v w2 = wread(wt1s, 200, sg, 2, lq);
            s8v w3 = wread(wt1s, 200, sg, 3, lq);
            s8v w4 = wread(wt1s, 200, sg, 4, lq);
            s8v w5 = wread(wt1s, 200, sg, 5, lq);
            a = mfma16(w0, x60, a);  a = mfma16(w1, x61, a);
            a = mfma16(w2, T7E0, a); a = mfma16(w3, T7E1, a);
            a = mfma16(w4, T7O0, a); a = mfma16(w5, T7O1, a);
            uint2 d; d.x = pk2(a[0], a[1]); d.y = pk2(a[2], a[3]);
            int col = (16*cc + 4*lq) ^ SWZ(r6);
            *(uint2*)(b6 + (size_t)r6 * 64 + col) = d;
        }
    }
    __syncthreads();

    // ================= l5 + l4 (one wave per tree) =================
    if (c == 0) {
        const u16* b6r = buf6 + tsel * 4096;
        s8v ch5[2][2][2];   // [tileE/O][hL/hR][s]
        #pragma unroll
        for (int d5 = 0; d5 < 2; d5++)
        #pragma unroll
        for (int pr = 0; pr < 2; pr++) {
            int row = 4*rho + 2*d5 + pr;
            int sw = SWZ(row);
            ch5[d5][pr][0] = *(const s8v*)(b6r + (size_t)row*64 + ((     8*lq) ^ sw));
            ch5[d5][pr][1] = *(const s8v*)(b6r + (size_t)row*64 + ((32 + 8*lq) ^ sw));
        }
        const float* xr5E = xb + (size_t)(31 + 2*rho) * 35;
        const float* xr5O = xr5E + 35;
        s8v x5E0 = xB0(xr5E, lq), x5E1 = xB1(xr5E, lq);
        s8v x5O0 = xB0(xr5O, lq), x5O1 = xB1(xr5O, lq);
        f4v aE[4], aO[4];
        #pragma unroll
        for (int i = 0; i < 4; i++) {
            f4v b = bias4(b1p + 32*(i>>1) + 8*lq + 4*(i&1));
            aE[i] = b; aO[i] = b;
        }
        #pragma unroll
        for (int i = 0; i < 4; i++) {
            int sg = sigp(rho, i>>1, i&1);
            s8v w0 = wread(wt1s, 200, sg, 0, lq);
            s8v w1 = wread(wt1s, 200, sg, 1, lq);
            s8v w2 = wread(wt1s, 200, sg, 2, lq);
            s8v w3 = wread(wt1s, 200, sg, 3, lq);
            s8v w4 = wread(wt1s, 200, sg, 4, lq);
            s8v w5 = wread(wt1s, 200, sg, 5, lq);
            aE[i] = mfma16(w0, x5E0, aE[i]); aE[i] = mfma16(w1, x5E1, aE[i]);
            aE[i] = mfma16(w2, ch5[0][0][0], aE[i]); aE[i] = mfma16(w3, ch5[0][0][1], aE[i]);
            aE[i] = mfma16(w4, ch5[0][1][0], aE[i]); aE[i] = mfma16(w5, ch5[0][1][1], aE[i]);
            aO[i] = mfma16(w0, x5O0, aO[i]); aO[i] = mfma16(w1, x5O1, aO[i]);
            aO[i] = mfma16(w2, ch5[1][0][0], aO[i]); aO[i] = mfma16(w3, ch5[1][0][1], aO[i]);
            aO[i] = mfma16(w4, ch5[1][1][0], aO[i]); aO[i] = mfma16(w5, ch5[1][1][1], aO[i]);
        }
        s8v L5E0 = pkfrag(aE[0], aE[1]), L5E1 = pkfrag(aE[2], aE[3]);
        s8v L5O0 = pkfrag(aO[0], aO[1]), L5O1 = pkfrag(aO[2], aO[3]);

        const float* xr4 = xb + (size_t)(15 + rho) * 35;
        s8v x40 = xB0(xr4, lq), x41 = xB1(xr4, lq);
        #pragma unroll
        for (int cc = 0; cc < 4; cc++) {
            f4v a = bias4(b1p + 16*cc + 4*lq);
            int sg = 16*cc + rho;
            s8v w0 = wread(wt1s, 200, sg, 0, lq);
            s8v w1 = wread(wt1s, 200, sg, 1, lq);
            s8v w2 = wread(wt1s, 200, sg, 2, lq);
            s8v w3 = wread(wt1s, 200, sg, 3, lq);
            s8v w4 = wread(wt1s, 200, sg, 4, lq);
            s8v w5 = wread(wt1s, 200, sg, 5, lq);
            a = mfma16(w0, x40, a);  a = mfma16(w1, x41, a);
            a = mfma16(w2, L5E0, a); a = mfma16(w3, L5E1, a);
            a = mfma16(w4, L5O0, a); a = mfma16(w5, L5O1, a);
            size_t base = ((size_t)tree*16 + rho) * 64 + 16*cc + 4*lq;
            *(u32*)(h4 + base)     = pk2(a[0], a[1]);
            *(u32*)(h4 + base + 2) = pk2(a[2], a[3]);
        }
    }
}

// ---------------------------------------------------------------------------
// k3: block = tree p, ONE wave. l3..l0 (unchanged, validated).
struct XL { float4 A, B, T; };
__device__ __forceinline__ s8v mk0(const XL& v) {
    s8v r;
    r[0]=(short)f2bf(v.A.x); r[1]=(short)f2bf(v.A.y); r[2]=(short)f2bf(v.A.z); r[3]=(short)f2bf(v.A.w);
    r[4]=(short)f2bf(v.B.x); r[5]=(short)f2bf(v.B.y); r[6]=(short)f2bf(v.B.z); r[7]=(short)f2bf(v.B.w);
    return r;
}
__device__ __forceinline__ s8v mk1(const XL& v) {
    s8v r = {0,0,0,0,0,0,0,0};
    r[0]=(short)f2bf(v.T.y); r[1]=(short)f2bf(v.T.z); r[2]=(short)f2bf(v.T.w);
    return r;
}

__global__ __launch_bounds__(64) void k3_tail(
    const float* __restrict__ x0,
    const u16* __restrict__ wt1, const float* __restrict__ b1p,
    const u16* __restrict__ h4, float* __restrict__ h0)
{
    __shared__ __align__(16) u16 tb0[32 * 64];
    __shared__ __align__(16) u16 tb1[32 * 64];
    const int l  = threadIdx.x;
    const int lq = l >> 4, lm = l & 15;
    const int p  = blockIdx.x;
    const float* xb = x0 + (size_t)p * 511 * 35;

    auto xload = [&](int lo) -> XL {
        const float* xr = xb + (size_t)(lo + lm) * 35;
        XL v;
        v.A = *(const float4*)(xr + lq * 8);
        v.B = *(const float4*)(xr + lq * 8 + 4);
        if (lq == 0) v.T = *(const float4*)(xr + 31);
        else         v.T = float4{0.f, 0.f, 0.f, 0.f};
        return v;
    };

    XL X3 = xload(7), X2 = xload(3), X1 = xload(1), X0v = xload(0);
    s8v ch[4];
    #pragma unroll
    for (int ks = 0; ks < 4; ks++) {
        int k0 = ks*32 + lq*8;
        int rr = 2*lm + (k0 >> 6);
        ch[ks] = *(const s8v*)(h4 + ((size_t)p*16 + rr)*64 + (k0 & 63));
    }

    s8v wB[6][4]; f4v bi[4];
    #pragma unroll
    for (int ct = 0; ct < 4; ct++) {
        int col = ct*16 + lm;
        #pragma unroll
        for (int ks = 0; ks < 6; ks++) wB[ks][ct] = *(const s8v*)(wt1 + col*192 + ks*32 + lq*8);
        float bv = b1p[col];
        bi[ct] = (f4v){bv, bv, bv, bv};
    }

    f4v acc[4];
    auto store_lds = [&](u16* buf) {
        #pragma unroll
        for (int r = 0; r < 4; r++) {
            int ro = lq*4 + r; int sw = SWZ(ro);
            #pragma unroll
            for (int ct = 0; ct < 4; ct++)
                buf[ro*64 + ((ct*16 + lm) ^ sw)] = f2bf(fmaxf(acc[ct][r], 0.f));
        }
        asm volatile("s_waitcnt lgkmcnt(0)" ::: "memory");
    };

    {
        s8v a0 = mk0(X3), a1 = mk1(X3);
        #pragma unroll
        for (int ct = 0; ct < 4; ct++) {
            acc[ct] = bi[ct];
            acc[ct] = mfma16(a0, wB[0][ct], acc[ct]);
            acc[ct] = mfma16(a1, wB[1][ct], acc[ct]);
        }
        #pragma unroll
        for (int ks = 0; ks < 4; ks++)
            #pragma unroll
            for (int ct = 0; ct < 4; ct++) acc[ct] = mfma16(ch[ks], wB[2 + ks][ct], acc[ct]);
        store_lds(tb0);
    }

    auto level = [&](const XL& xv, const u16* bufR) {
        s8v a0 = mk0(xv), a1 = mk1(xv);
        #pragma unroll
        for (int ct = 0; ct < 4; ct++) {
            acc[ct] = bi[ct];
            acc[ct] = mfma16(a0, wB[0][ct], acc[ct]);
            acc[ct] = mfma16(a1, wB[1][ct], acc[ct]);
        }
        #pragma unroll
        for (int ks = 0; ks < 4; ks++) {
            int k0 = ks*32 + lq*8;
            int rr = 2*lm + (k0 >> 6);
            s8v a = *(const s8v*)(bufR + rr*64 + ((k0 & 63) ^ SWZ(rr)));
            #pragma unroll
            for (int ct = 0; ct < 4; ct++) acc[ct] = mfma16(a, wB[2 + ks][ct], acc[ct]);
        }
    };
    level(X2, tb0); store_lds(tb1);
    level(X1, tb1); store_lds(tb0);
    level(X0v, tb0);
    if (lq == 0) {
        #pragma unroll
        for (int ct = 0; ct < 4; ct++)
            h0[(size_t)p*64 + ct*16 + lm] = fmaxf(acc[ct][0], 0.f);
    }
}

// ---------------------------------------------------------------------------
__global__ void mean_kernel(const float* __restrict__ h0, float* __restrict__ mh)
{
    int idx = blockIdx.x * blockDim.x + threadIdx.x;   // 512*64
    if (idx < 512 * 64) {
        int g = idx >> 6, h = idx & 63;
        float s = 0.f;
        #pragma unroll
        for (int q = 0; q < 5; q++) s += h0[(size_t)(g * 5 + q) * 64 + h];
        mh[idx] = s * 0.2f;
    }
}

__global__ __launch_bounds__(64) void head_kernel(const float* __restrict__ x,
                                                  const float* __restrict__ mh,
                                                  const float* __restrict__ Wfc1,
                                                  const float* __restrict__ bfc1,
                                                  const float* __restrict__ Wfc2,
                                                  const float* __restrict__ bfc2,
                                                  float* __restrict__ out)
{
    __shared__ float sw[64];
    __shared__ float sh[64];
    int b = blockIdx.x, h = threadIdx.x;

    float a0 = 0.f, a1 = 0.f, a2 = 0.f, a3 = 0.f;
    const float* xr = x + (size_t)b * 512;
    for (int g = 0; g < 512; g += 4) {
        a0 = fmaf(xr[g + 0], mh[(g + 0) * 64 + h], a0);
        a1 = fmaf(xr[g + 1], mh[(g + 1) * 64 + h], a1);
        a2 = fmaf(xr[g + 2], mh[(g + 2) * 64 + h], a2);
        a3 = fmaf(xr[g + 3], mh[(g + 3) * 64 + h], a3);
    }
    sw[h] = (a0 + a1) + (a2 + a3);
    __syncthreads();

    float acc = bfc1[h];
    #pragma unroll 8
    for (int k = 0; k < 64; k++) acc = fmaf(Wfc1[h * 64 + k], sw[k], acc);
    sh[h] = fmaxf(acc, 0.f);
    __syncthreads();

    if (h < 8) {
        float o = bfc2[h];
        #pragma unroll 8
        for (int f = 0; f < 64; f++) o = fmaf(Wfc2[h * 64 + f], sh[f], o);
        out[(size_t)b * 8 + h] = o;
    }
}

// ---------------------------------------------------------------------------
extern "C" void kernel_launch(void* const* d_in, const int* in_sizes, int n_in,
                              void* d_out, int out_size, void* d_ws, size_t ws_size,
                              hipStream_t stream)
{
    (void)in_sizes; (void)n_in; (void)out_size; (void)ws_size;
    const float* x     = (const float*)d_in[0];
    const float* x0    = (const float*)d_in[1];
    const float* W_emb = (const float*)d_in[2];
    const float* b_emb = (const float*)d_in[3];
    const float* W0    = (const float*)d_in[4];
    const float* b0    = (const float*)d_in[5];
    const float* W1    = (const float*)d_in[6];
    const float* b1    = (const float*)d_in[7];
    const float* Wfc1  = (const float*)d_in[8];
    const float* bfc1  = (const float*)d_in[9];
    const float* Wfc2  = (const float*)d_in[10];
    const float* bfc2  = (const float*)d_in[11];
    float* out = (float*)d_out;

    u16* wt1   = (u16*)d_ws;                 // 64*192
    u16* wt0   = wt1 + 64 * 192;             // 64*64
    float* b1p = (float*)(wt0 + 64 * 64);
    float* b0p = b1p + 64;
    u16* h4    = (u16*)(b0p + 64);           // 2560*16*64 bf16
    float* h0  = (float*)(h4 + (size_t)2560 * 16 * 64);   // 2560*64 f32
    float* mh  = h0 + 2560 * 64;             // 512*64 f32

    prep_kernel<<<65, 256, 0, stream>>>(W_emb, b_emb, W0, b0, W1, b1, wt1, wt0, b1p, b0p);
    tree_chain<<<1280, 512, 0, stream>>>(x0, wt1, wt0, b1p, b0p, h4);
    k3_tail<<<2560, 64, 0, stream>>>(x0, wt1, b1p, h4, h0);
    mean_kernel<<<128, 256, 0, stream>>>(h0, mh);
    head_kernel<<<512, 64, 0, stream>>>(x, mh, Wfc1, bfc1, Wfc2, bfc2, out);
}

// Round 11
// 88.707 us; speedup vs baseline: 3.1523x; 1.0787x over previous
//
#include <hip/hip_runtime.h>
#include <hip/hip_bf16.h>

// ---------------------------------------------------------------------------
// Round 11: R10 chains + (1) 2 trees per wave (halves LDS weight-read traffic
// per tree; x-part/TL-part pass split keeps VGPR <= ~116), (2) l3..l0 tail
// fused into the block (wt1s reused from LDS, h4 image overlaid on buf6
// slice) -> k3_tail kernel deleted. Block = 4 trees, 8 waves, LDS 62 KB.
// ---------------------------------------------------------------------------

typedef __attribute__((ext_vector_type(8))) short s8v;   // 8 bf16
typedef __attribute__((ext_vector_type(4))) float f4v;   // MFMA C/D
typedef unsigned short u16;
typedef unsigned int   u32;

__device__ __forceinline__ u16 f2bf(float f) {
    return __builtin_bit_cast(u16, __float2bfloat16(f));
}
__device__ __forceinline__ f4v mfma16(s8v a, s8v b, f4v c) {
    return __builtin_amdgcn_mfma_f32_16x16x32_bf16(a, b, c, 0, 0, 0);
}
#define SWZ(r) ((((r) & 1) | (((r) >> 1) & 6)) << 3)

__device__ __forceinline__ u32 pk2(float a, float b) {
    return (u32)f2bf(fmaxf(a, 0.f)) | ((u32)f2bf(fmaxf(b, 0.f)) << 16);
}
__device__ __forceinline__ s8v pkfrag(f4v h0, f4v h1) {
    int4 d;
    d.x = (int)pk2(h0[0], h0[1]); d.y = (int)pk2(h0[2], h0[3]);
    d.z = (int)pk2(h1[0], h1[1]); d.w = (int)pk2(h1[2], h1[3]);
    return __builtin_bit_cast(s8v, d);
}
__device__ __forceinline__ s8v xB0(const float* __restrict__ xr, int lq) {
    float4 A = *(const float4*)(xr + lq * 8);
    float4 B = *(const float4*)(xr + lq * 8 + 4);
    s8v r;
    r[0]=(short)f2bf(A.x); r[1]=(short)f2bf(A.y); r[2]=(short)f2bf(A.z); r[3]=(short)f2bf(A.w);
    r[4]=(short)f2bf(B.x); r[5]=(short)f2bf(B.y); r[6]=(short)f2bf(B.z); r[7]=(short)f2bf(B.w);
    return r;
}
__device__ __forceinline__ s8v xB1(const float* __restrict__ xr, int lq) {
    s8v r = (s8v){0,0,0,0,0,0,0,0};
    if (lq == 0) {
        float4 T = *(const float4*)(xr + 31);   // k31..34
        r[0]=(short)f2bf(T.y); r[1]=(short)f2bf(T.z); r[2]=(short)f2bf(T.w);
    }
    return r;
}
__device__ __forceinline__ s8v wread(const u16* w, int stride, int row, int ks, int lq) {
    return *(const s8v*)(w + row * stride + ks * 32 + lq * 8);
}
__device__ __forceinline__ f4v bias4(const float* __restrict__ b) {
    float4 t = *(const float4*)b; return (f4v){t.x, t.y, t.z, t.w};
}
__device__ __forceinline__ int sigp(int rho, int s, int h) {
    return 32*s + 4*h + ((rho & 12) << 1) + (rho & 3);
}

// ---------------------------------------------------------------------------
__global__ void prep_kernel(const float* __restrict__ W_emb, const float* __restrict__ b_emb,
                            const float* __restrict__ W0, const float* __restrict__ b0,
                            const float* __restrict__ W1, const float* __restrict__ b1,
                            u16* __restrict__ wt1, u16* __restrict__ wt0,
                            float* __restrict__ b1p, float* __restrict__ b0p)
{
    int idx = blockIdx.x * 256 + threadIdx.x;
    if (idx < 64 * 192) {
        int h = idx / 192, k = idx % 192;
        float v;
        if (k < 32) { v = 0.f; for (int e = 0; e < 64; e++) v = fmaf(W1[h*195+e], W_emb[e*32+k], v); }
        else if (k < 35)  v = W1[h*195 + 64 + (k - 32)];
        else if (k < 64)  v = 0.f;
        else              v = W1[h*195 + 67 + (k - 64)];   // hL(64) then hR(64)
        wt1[h*192 + k] = f2bf(v);
    } else if (idx < 64*192 + 64*64) {
        int j = idx - 64*192; int h = j >> 6, k = j & 63;
        float v;
        if (k < 32)      { v = 0.f; for (int e = 0; e < 64; e++) v = fmaf(W0[h*67+e], W_emb[e*32+k], v); }
        else if (k < 35)   v = W0[h*67 + 64 + (k - 32)];
        else               v = 0.f;
        wt0[h*64 + k] = f2bf(v);
    } else if (idx < 64*192 + 64*64 + 64) {
        int h = idx - (64*192 + 64*64);
        float v = b1[h];
        for (int e = 0; e < 64; e++) v = fmaf(W1[h*195+e], b_emb[e], v);
        b1p[h] = v;
    } else if (idx < 64*192 + 64*64 + 128) {
        int h = idx - (64*192 + 64*64 + 64);
        float v = b0[h];
        for (int e = 0; e < 64; e++) v = fmaf(W0[h*67+e], b_emb[e], v);
        b0p[h] = v;
    }
}

// ---------------------------------------------------------------------------
__global__ __launch_bounds__(512, 2) void tree_all(
    const float* __restrict__ x0,
    const u16* __restrict__ wt1g, const u16* __restrict__ wt0g,
    const float* __restrict__ b1p, const float* __restrict__ b0p,
    float* __restrict__ h0out)
{
    __shared__ __align__(16) u16 wt1s[64 * 200];        // 25.6 KB, pad stride 200
    __shared__ __align__(16) u16 wt0s[64 * 40 + 64];    // 5.25 KB + guard
    __shared__ __align__(16) u16 buf6[4 * 64 * 64];     // 32 KB: 4 tree-slices

    const int tid = threadIdx.x;
    const int l   = tid & 63;
    const int w   = tid >> 6;      // 0..7
    const int lq  = l >> 4;
    const int rho = l & 15;
    const int pair = w >> 2;       // tree-pair within block
    const int c    = w & 3;        // chain
    const int tA = blockIdx.x * 4 + 2 * pair;
    const int tB = tA + 1;
    const float* xbA = x0 + (size_t)tA * 511 * 35;
    const float* xbB = x0 + (size_t)tB * 511 * 35;

    // ---- stage weights (coalesced dwords) ----
    {
        u32* d1 = (u32*)wt1s; const u32* s1 = (const u32*)wt1g;
        #pragma unroll
        for (int t = 0; t < 12; t++) {
            int i = t*512 + tid;                 // 6144 dwords exactly
            int row = i / 96, kk = i - row*96;
            d1[row*100 + kk] = s1[row*96 + kk];
        }
        u32* d0 = (u32*)wt0s; const u32* s0 = (const u32*)wt0g;
        #pragma unroll
        for (int t = 0; t < 3; t++) {
            int i = t*512 + tid;
            if (i < 1280) { int row = i / 20, kk = i - row*20; d0[row*20 + kk] = s0[row*32 + kk]; }
        }
        if (tid < 32) ((u32*)(wt0s + 64*40))[tid] = 0;   // guard
    }
    __syncthreads();

    // ================= leaf (both trees share WL) =================
    s8v TLA[4][2], TLB[4][2];
    {
        s8v WL[4][2]; f4v bL[4];
        #pragma unroll
        for (int i = 0; i < 4; i++) {
            int sg = sigp(rho, i >> 1, i & 1);
            WL[i][0] = wread(wt0s, 40, sg, 0, lq);
            WL[i][1] = wread(wt0s, 40, sg, 1, lq);
            bL[i] = bias4(b0p + 32*(i>>1) + 8*lq + 4*(i&1));
        }
        #pragma unroll
        for (int q = 0; q < 4; q++) {
            const float* xrA = xbA + (size_t)(255 + 64*c + 4*rho + q) * 35;
            const float* xrB = xbB + (size_t)(255 + 64*c + 4*rho + q) * 35;
            s8v xaA = xB0(xrA, lq), xtA = xB1(xrA, lq);
            s8v xaB = xB0(xrB, lq), xtB = xB1(xrB, lq);
            f4v aA[4], aB[4];
            #pragma unroll
            for (int i = 0; i < 4; i++) { aA[i] = bL[i]; aB[i] = bL[i]; }
            #pragma unroll
            for (int i = 0; i < 4; i++) {
                aA[i] = mfma16(WL[i][0], xaA, aA[i]);
                aA[i] = mfma16(WL[i][1], xtA, aA[i]);
                aB[i] = mfma16(WL[i][0], xaB, aB[i]);
                aB[i] = mfma16(WL[i][1], xtB, aB[i]);
            }
            TLA[q][0] = pkfrag(aA[0], aA[1]); TLA[q][1] = pkfrag(aA[2], aA[3]);
            TLB[q][0] = pkfrag(aB[0], aB[1]); TLB[q][1] = pkfrag(aB[2], aB[3]);
        }
    }

    // ================= l7 (both trees; x-pass then TL-pass) =================
    s8v A7[4], B7[4];   // [E0,E1,O0,O1]
    {
        f4v aAE[4], aAO[4], aBE[4], aBO[4];
        #pragma unroll
        for (int i = 0; i < 4; i++) {
            f4v b = bias4(b1p + 32*(i>>1) + 8*lq + 4*(i&1));
            aAE[i] = b; aAO[i] = b; aBE[i] = b; aBO[i] = b;
        }
        {   // pass 1: x-part
            const float* xrAE = xbA + (size_t)(127 + 32*c + 2*rho) * 35;
            const float* xrBE = xbB + (size_t)(127 + 32*c + 2*rho) * 35;
            s8v xAE0 = xB0(xrAE, lq),      xAE1 = xB1(xrAE, lq);
            s8v xAO0 = xB0(xrAE + 35, lq), xAO1 = xB1(xrAE + 35, lq);
            s8v xBE0 = xB0(xrBE, lq),      xBE1 = xB1(xrBE, lq);
            s8v xBO0 = xB0(xrBE + 35, lq), xBO1 = xB1(xrBE + 35, lq);
            #pragma unroll
            for (int i = 0; i < 4; i++) {
                int sg = sigp(rho, i >> 1, i & 1);
                s8v w0 = wread(wt1s, 200, sg, 0, lq);
                s8v w1 = wread(wt1s, 200, sg, 1, lq);
                aAE[i] = mfma16(w0, xAE0, aAE[i]); aAE[i] = mfma16(w1, xAE1, aAE[i]);
                aAO[i] = mfma16(w0, xAO0, aAO[i]); aAO[i] = mfma16(w1, xAO1, aAO[i]);
                aBE[i] = mfma16(w0, xBE0, aBE[i]); aBE[i] = mfma16(w1, xBE1, aBE[i]);
                aBO[i] = mfma16(w0, xBO0, aBO[i]); aBO[i] = mfma16(w1, xBO1, aBO[i]);
            }
        }
        // pass 2: TL-part (each w read feeds 4 MFMAs)
        #pragma unroll
        for (int i = 0; i < 4; i++) {
            int sg = sigp(rho, i >> 1, i & 1);
            s8v w2 = wread(wt1s, 200, sg, 2, lq);
            s8v w3 = wread(wt1s, 200, sg, 3, lq);
            s8v w4 = wread(wt1s, 200, sg, 4, lq);
            s8v w5 = wread(wt1s, 200, sg, 5, lq);
            aAE[i] = mfma16(w2, TLA[0][0], aAE[i]); aAE[i] = mfma16(w3, TLA[0][1], aAE[i]);
            aAE[i] = mfma16(w4, TLA[1][0], aAE[i]); aAE[i] = mfma16(w5, TLA[1][1], aAE[i]);
            aAO[i] = mfma16(w2, TLA[2][0], aAO[i]); aAO[i] = mfma16(w3, TLA[2][1], aAO[i]);
            aAO[i] = mfma16(w4, TLA[3][0], aAO[i]); aAO[i] = mfma16(w5, TLA[3][1], aAO[i]);
            aBE[i] = mfma16(w2, TLB[0][0], aBE[i]); aBE[i] = mfma16(w3, TLB[0][1], aBE[i]);
            aBE[i] = mfma16(w4, TLB[1][0], aBE[i]); aBE[i] = mfma16(w5, TLB[1][1], aBE[i]);
            aBO[i] = mfma16(w2, TLB[2][0], aBO[i]); aBO[i] = mfma16(w3, TLB[2][1], aBO[i]);
            aBO[i] = mfma16(w4, TLB[3][0], aBO[i]); aBO[i] = mfma16(w5, TLB[3][1], aBO[i]);
        }
        A7[0] = pkfrag(aAE[0], aAE[1]); A7[1] = pkfrag(aAE[2], aAE[3]);
        A7[2] = pkfrag(aAO[0], aAO[1]); A7[3] = pkfrag(aAO[2], aAO[3]);
        B7[0] = pkfrag(aBE[0], aBE[1]); B7[1] = pkfrag(aBE[2], aBE[3]);
        B7[2] = pkfrag(aBO[0], aBO[1]); B7[3] = pkfrag(aBO[2], aBO[3]);
    }

    // ================= l6 (both trees) -> buf6 slices =================
    {
        const float* xrA6 = xbA + (size_t)(63 + 16*c + rho) * 35;
        const float* xrB6 = xbB + (size_t)(63 + 16*c + rho) * 35;
        s8v xA0 = xB0(xrA6, lq), xA1 = xB1(xrA6, lq);
        s8v xBv0 = xB0(xrB6, lq), xBv1 = xB1(xrB6, lq);
        u16* slA = buf6 + (2*pair) * 4096;
        u16* slB = slA + 4096;
        int r6 = 16*c + rho;
        int sw6 = SWZ(r6);
        #pragma unroll
        for (int cc = 0; cc < 4; cc++) {
            int sg = 16*cc + rho;
            s8v w0 = wread(wt1s, 200, sg, 0, lq);
            s8v w1 = wread(wt1s, 200, sg, 1, lq);
            s8v w2 = wread(wt1s, 200, sg, 2, lq);
            s8v w3 = wread(wt1s, 200, sg, 3, lq);
            s8v w4 = wread(wt1s, 200, sg, 4, lq);
            s8v w5 = wread(wt1s, 200, sg, 5, lq);
            f4v bb = bias4(b1p + 16*cc + 4*lq);
            f4v aA = bb, aB = bb;
            aA = mfma16(w0, xA0, aA);  aA = mfma16(w1, xA1, aA);
            aA = mfma16(w2, A7[0], aA); aA = mfma16(w3, A7[1], aA);
            aA = mfma16(w4, A7[2], aA); aA = mfma16(w5, A7[3], aA);
            aB = mfma16(w0, xBv0, aB); aB = mfma16(w1, xBv1, aB);
            aB = mfma16(w2, B7[0], aB); aB = mfma16(w3, B7[1], aB);
            aB = mfma16(w4, B7[2], aB); aB = mfma16(w5, B7[3], aB);
            int col = (16*cc + 4*lq) ^ sw6;
            uint2 dA; dA.x = pk2(aA[0], aA[1]); dA.y = pk2(aA[2], aA[3]);
            uint2 dB; dB.x = pk2(aB[0], aB[1]); dB.y = pk2(aB[2], aB[3]);
            *(uint2*)(slA + (size_t)r6 * 64 + col) = dA;
            *(uint2*)(slB + (size_t)r6 * 64 + col) = dB;
        }
    }
    __syncthreads();

    // ================= tail: waves 0..3, one tree each =================
    if (w < 4) {
        const int tree = blockIdx.x * 4 + w;
        u16* slice = buf6 + w * 4096;
        const float* xb = x0 + (size_t)tree * 511 * 35;

        // ---- l5 ----
        s8v ch5[2][2][2];
        #pragma unroll
        for (int d5 = 0; d5 < 2; d5++)
        #pragma unroll
        for (int pr = 0; pr < 2; pr++) {
            int row = 4*rho + 2*d5 + pr;
            int sw = SWZ(row);
            ch5[d5][pr][0] = *(const s8v*)(slice + (size_t)row*64 + ((     8*lq) ^ sw));
            ch5[d5][pr][1] = *(const s8v*)(slice + (size_t)row*64 + ((32 + 8*lq) ^ sw));
        }
        const float* xr5E = xb + (size_t)(31 + 2*rho) * 35;
        s8v x5E0 = xB0(xr5E, lq),      x5E1 = xB1(xr5E, lq);
        s8v x5O0 = xB0(xr5E + 35, lq), x5O1 = xB1(xr5E + 35, lq);
        f4v aE[4], aO[4];
        #pragma unroll
        for (int i = 0; i < 4; i++) {
            f4v b = bias4(b1p + 32*(i>>1) + 8*lq + 4*(i&1));
            aE[i] = b; aO[i] = b;
        }
        #pragma unroll
        for (int i = 0; i < 4; i++) {
            int sg = sigp(rho, i >> 1, i & 1);
            s8v w0 = wread(wt1s, 200, sg, 0, lq);
            s8v w1 = wread(wt1s, 200, sg, 1, lq);
            s8v w2 = wread(wt1s, 200, sg, 2, lq);
            s8v w3 = wread(wt1s, 200, sg, 3, lq);
            s8v w4 = wread(wt1s, 200, sg, 4, lq);
            s8v w5 = wread(wt1s, 200, sg, 5, lq);
            aE[i] = mfma16(w0, x5E0, aE[i]); aE[i] = mfma16(w1, x5E1, aE[i]);
            aE[i] = mfma16(w2, ch5[0][0][0], aE[i]); aE[i] = mfma16(w3, ch5[0][0][1], aE[i]);
            aE[i] = mfma16(w4, ch5[0][1][0], aE[i]); aE[i] = mfma16(w5, ch5[0][1][1], aE[i]);
            aO[i] = mfma16(w0, x5O0, aO[i]); aO[i] = mfma16(w1, x5O1, aO[i]);
            aO[i] = mfma16(w2, ch5[1][0][0], aO[i]); aO[i] = mfma16(w3, ch5[1][0][1], aO[i]);
            aO[i] = mfma16(w4, ch5[1][1][0], aO[i]); aO[i] = mfma16(w5, ch5[1][1][1], aO[i]);
        }
        s8v L5E0 = pkfrag(aE[0], aE[1]), L5E1 = pkfrag(aE[2], aE[3]);
        s8v L5O0 = pkfrag(aO[0], aO[1]), L5O1 = pkfrag(aO[2], aO[3]);

        // ---- l4 -> h4 image in slice rows 0..15 (SWZ'd) ----
        {
            const float* xr4 = xb + (size_t)(15 + rho) * 35;
            s8v x40 = xB0(xr4, lq), x41 = xB1(xr4, lq);
            int sw4 = SWZ(rho);
            #pragma unroll
            for (int cc = 0; cc < 4; cc++) {
                int sg = 16*cc + rho;
                s8v w0 = wread(wt1s, 200, sg, 0, lq);
                s8v w1 = wread(wt1s, 200, sg, 1, lq);
                s8v w2 = wread(wt1s, 200, sg, 2, lq);
                s8v w3 = wread(wt1s, 200, sg, 3, lq);
                s8v w4 = wread(wt1s, 200, sg, 4, lq);
                s8v w5 = wread(wt1s, 200, sg, 5, lq);
                f4v a = bias4(b1p + 16*cc + 4*lq);
                a = mfma16(w0, x40, a);  a = mfma16(w1, x41, a);
                a = mfma16(w2, L5E0, a); a = mfma16(w3, L5E1, a);
                a = mfma16(w4, L5O0, a); a = mfma16(w5, L5O1, a);
                int col = (16*cc + 4*lq) ^ sw4;
                uint2 d; d.x = pk2(a[0], a[1]); d.y = pk2(a[2], a[3]);
                *(uint2*)(slice + (size_t)rho * 64 + col) = d;
            }
        }
        asm volatile("s_waitcnt lgkmcnt(0)" ::: "memory");

        // ---- l3..l0 (k3 form: A=activations, B=weights from wt1s) ----
        u16* tb0 = slice + 32 * 64;   // rows 32..63
        u16* tb1 = slice;             // rows 0..31 (h4 image dead after l3)
        float bv[4];
        #pragma unroll
        for (int ct = 0; ct < 4; ct++) bv[ct] = b1p[ct*16 + rho];
        f4v acc[4];

        auto tlevel = [&](int lo, const u16* cb) {
            const float* xr = xb + (size_t)(lo + rho) * 35;
            s8v a0 = xB0(xr, lq), a1 = xB1(xr, lq);
            #pragma unroll
            for (int ct = 0; ct < 4; ct++) acc[ct] = (f4v){bv[ct], bv[ct], bv[ct], bv[ct]};
            #pragma unroll
            for (int ct = 0; ct < 4; ct++) {
                acc[ct] = mfma16(a0, wread(wt1s, 200, ct*16 + rho, 0, lq), acc[ct]);
                acc[ct] = mfma16(a1, wread(wt1s, 200, ct*16 + rho, 1, lq), acc[ct]);
            }
            #pragma unroll
            for (int ks = 0; ks < 4; ks++) {
                int k0 = ks*32 + lq*8;
                int rr = 2*rho + (k0 >> 6);
                s8v ach = *(const s8v*)(cb + (size_t)rr*64 + ((k0 & 63) ^ SWZ(rr)));
                #pragma unroll
                for (int ct = 0; ct < 4; ct++)
                    acc[ct] = mfma16(ach, wread(wt1s, 200, ct*16 + rho, 2 + ks, lq), acc[ct]);
            }
        };
        auto tstore = [&](u16* buf) {
            #pragma unroll
            for (int r = 0; r < 4; r++) {
                int ro = lq*4 + r; int sw = SWZ(ro);
                #pragma unroll
                for (int ct = 0; ct < 4; ct++)
                    buf[ro*64 + ((ct*16 + rho) ^ sw)] = f2bf(fmaxf(acc[ct][r], 0.f));
            }
            asm volatile("s_waitcnt lgkmcnt(0)" ::: "memory");
        };

        tlevel(7, slice);  tstore(tb0);   // l3 (children = h4 image rows 0..15)
        tlevel(3, tb0);    tstore(tb1);   // l2
        tlevel(1, tb1);    tstore(tb0);   // l1
        tlevel(0, tb0);                   // l0
        if (lq == 0) {
            #pragma unroll
            for (int ct = 0; ct < 4; ct++)
                h0out[(size_t)tree*64 + ct*16 + rho] = fmaxf(acc[ct][0], 0.f);
        }
    }
}

// ---------------------------------------------------------------------------
__global__ void mean_kernel(const float* __restrict__ h0, float* __restrict__ mh)
{
    int idx = blockIdx.x * blockDim.x + threadIdx.x;   // 512*64
    if (idx < 512 * 64) {
        int g = idx >> 6, h = idx & 63;
        float s = 0.f;
        #pragma unroll
        for (int q = 0; q < 5; q++) s += h0[(size_t)(g * 5 + q) * 64 + h];
        mh[idx] = s * 0.2f;
    }
}

__global__ __launch_bounds__(64) void head_kernel(const float* __restrict__ x,
                                                  const float* __restrict__ mh,
                                                  const float* __restrict__ Wfc1,
                                                  const float* __restrict__ bfc1,
                                                  const float* __restrict__ Wfc2,
                                                  const float* __restrict__ bfc2,
                                                  float* __restrict__ out)
{
    __shared__ float sw[64];
    __shared__ float sh[64];
    int b = blockIdx.x, h = threadIdx.x;

    float a0 = 0.f, a1 = 0.f, a2 = 0.f, a3 = 0.f;
    const float* xr = x + (size_t)b * 512;
    for (int g = 0; g < 512; g += 4) {
        a0 = fmaf(xr[g + 0], mh[(g + 0) * 64 + h], a0);
        a1 = fmaf(xr[g + 1], mh[(g + 1) * 64 + h], a1);
        a2 = fmaf(xr[g + 2], mh[(g + 2) * 64 + h], a2);
        a3 = fmaf(xr[g + 3], mh[(g + 3) * 64 + h], a3);
    }
    sw[h] = (a0 + a1) + (a2 + a3);
    __syncthreads();

    float acc = bfc1[h];
    #pragma unroll 8
    for (int k = 0; k < 64; k++) acc = fmaf(Wfc1[h * 64 + k], sw[k], acc);
    sh[h] = fmaxf(acc, 0.f);
    __syncthreads();

    if (h < 8) {
        float o = bfc2[h];
        #pragma unroll 8
        for (int f = 0; f < 64; f++) o = fmaf(Wfc2[h * 64 + f], sh[f], o);
        out[(size_t)b * 8 + h] = o;
    }
}

// ---------------------------------------------------------------------------
extern "C" void kernel_launch(void* const* d_in, const int* in_sizes, int n_in,
                              void* d_out, int out_size, void* d_ws, size_t ws_size,
                              hipStream_t stream)
{
    (void)in_sizes; (void)n_in; (void)out_size; (void)ws_size;
    const float* x     = (const float*)d_in[0];
    const float* x0    = (const float*)d_in[1];
    const float* W_emb = (const float*)d_in[2];
    const float* b_emb = (const float*)d_in[3];
    const float* W0    = (const float*)d_in[4];
    const float* b0    = (const float*)d_in[5];
    const float* W1    = (const float*)d_in[6];
    const float* b1    = (const float*)d_in[7];
    const float* Wfc1  = (const float*)d_in[8];
    const float* bfc1  = (const float*)d_in[9];
    const float* Wfc2  = (const float*)d_in[10];
    const float* bfc2  = (const float*)d_in[11];
    float* out = (float*)d_out;

    u16* wt1   = (u16*)d_ws;                 // 64*192
    u16* wt0   = wt1 + 64 * 192;             // 64*64
    float* b1p = (float*)(wt0 + 64 * 64);
    float* b0p = b1p + 64;
    float* h0  = b0p + 64;                   // 2560*64 f32
    float* mh  = h0 + 2560 * 64;             // 512*64 f32

    prep_kernel<<<65, 256, 0, stream>>>(W_emb, b_emb, W0, b0, W1, b1, wt1, wt0, b1p, b0p);
    tree_all<<<640, 512, 0, stream>>>(x0, wt1, wt0, b1p, b0p, h0);
    mean_kernel<<<128, 256, 0, stream>>>(h0, mh);
    head_kernel<<<512, 64, 0, stream>>>(x, mh, Wfc1, bfc1, Wfc2, bfc2, out);
}